// Round 1
// baseline (1418.827 us; speedup 1.0000x reference)
//
#include <hip/hip_runtime.h>

#define N_NODES 100000
#define N_EDGES 1600000
#define N_GRAPHS 256
#define F_IN 38
#define HID 64

// ---------------------------------------------------------------------------
// Stage 2: agg1[dst][f] += x[src][f], one thread per (edge, feature)
// ---------------------------------------------------------------------------
__global__ void scatter1_kernel(const float* __restrict__ x,
                                const int* __restrict__ src,
                                const int* __restrict__ dst,
                                float* __restrict__ agg1) {
    int tid = blockIdx.x * blockDim.x + threadIdx.x;
    const int total = N_EDGES * F_IN;  // 60.8M < 2^31
    if (tid >= total) return;
    int e = tid / F_IN;        // compiler magic-mul
    int f = tid - e * F_IN;
    int s = src[e];
    int d = dst[e];
    atomicAdd(&agg1[d * F_IN + f], x[s * F_IN + f]);
}

// ---------------------------------------------------------------------------
// Stage 4: agg2[dst][f] += h[src][f], one thread per (edge, feature)
// ---------------------------------------------------------------------------
__global__ void scatter2_kernel(const float* __restrict__ h,
                                const int* __restrict__ src,
                                const int* __restrict__ dst,
                                float* __restrict__ agg2) {
    int tid = blockIdx.x * blockDim.x + threadIdx.x;
    const int total = N_EDGES * HID;   // 102.4M < 2^31
    if (tid >= total) return;
    int e = tid >> 6;
    int f = tid & 63;
    int s = src[e];
    int d = dst[e];
    atomicAdd(&agg2[(d << 6) + f], h[(s << 6) + f]);
}

// ---------------------------------------------------------------------------
// Stage 3: h = relu(agg1 @ w1_rel + b1 + x @ w1_root)
// block = 256 threads = 4 node-groups x 64 channels; 64 nodes per block
// ---------------------------------------------------------------------------
__global__ void dense1_kernel(const float* __restrict__ x,
                              const float* __restrict__ agg1,
                              const float* __restrict__ w_rel,
                              const float* __restrict__ b_rel,
                              const float* __restrict__ w_root,
                              float* __restrict__ h) {
    __shared__ float s_wrel[F_IN * HID];   // 9.5 KB
    __shared__ float s_wroot[F_IN * HID];  // 9.5 KB
    for (int i = threadIdx.x; i < F_IN * HID; i += 256) {
        s_wrel[i] = w_rel[i];
        s_wroot[i] = w_root[i];
    }
    __syncthreads();

    const int c = threadIdx.x & 63;
    const int r = threadIdx.x >> 6;       // 0..3
    const int base = blockIdx.x * 64;
    const float bias = b_rel[c];

    for (int i = 0; i < 16; ++i) {
        int n = base + r * 16 + i;
        if (n >= N_NODES) break;
        const float* ar = agg1 + n * F_IN;
        const float* xr = x + n * F_IN;
        float acc = bias;
        #pragma unroll
        for (int k = 0; k < F_IN; ++k) {
            acc += ar[k] * s_wrel[k * HID + c];
            acc += xr[k] * s_wroot[k * HID + c];
        }
        h[(n << 6) + c] = fmaxf(acc, 0.0f);
    }
}

// ---------------------------------------------------------------------------
// Stage 5: per-graph: sum_n relu-less layer2 rows, then mean + relu.
// batch is sorted -> node range of graph g via binary search; count = end-start.
// One block per graph, 256 threads = 4 node-groups x 64 channels.
// ---------------------------------------------------------------------------
__device__ __forceinline__ int lower_bound_i(const int* __restrict__ a, int n, int v) {
    int lo = 0, hi = n;
    while (lo < hi) {
        int mid = (lo + hi) >> 1;
        if (a[mid] < v) lo = mid + 1; else hi = mid;
    }
    return lo;
}

__global__ void layer2_pool_kernel(const float* __restrict__ h,
                                   const float* __restrict__ agg2,
                                   const float* __restrict__ w_rel,
                                   const float* __restrict__ b_rel,
                                   const float* __restrict__ w_root,
                                   const int* __restrict__ batch,
                                   float* __restrict__ out) {
    __shared__ float s_wrel[HID * HID];    // 16 KB
    __shared__ float s_wroot[HID * HID];   // 16 KB
    __shared__ float s_red[256];

    const int g = blockIdx.x;
    for (int i = threadIdx.x; i < HID * HID; i += 256) {
        s_wrel[i] = w_rel[i];
        s_wroot[i] = w_root[i];
    }

    // every thread computes the same bounds (uniform)
    const int start = lower_bound_i(batch, N_NODES, g);
    const int end   = lower_bound_i(batch, N_NODES, g + 1);
    __syncthreads();

    const int c = threadIdx.x & 63;
    const int r = threadIdx.x >> 6;
    const float bias = b_rel[c];

    float acc = 0.0f;
    for (int n = start + r; n < end; n += 4) {
        const float* ar = agg2 + (n << 6);
        const float* hr = h + (n << 6);
        float v = bias;
        #pragma unroll
        for (int k = 0; k < HID; ++k) {
            v += ar[k] * s_wrel[k * HID + c];
            v += hr[k] * s_wroot[k * HID + c];
        }
        acc += v;
    }

    s_red[threadIdx.x] = acc;
    __syncthreads();
    if (r == 0) {
        float s = s_red[c] + s_red[64 + c] + s_red[128 + c] + s_red[192 + c];
        int cnt = end - start;
        float denom = cnt > 0 ? (float)cnt : 1.0f;
        out[g * HID + c] = fmaxf(s / denom, 0.0f);
    }
}

// ---------------------------------------------------------------------------
extern "C" void kernel_launch(void* const* d_in, const int* in_sizes, int n_in,
                              void* d_out, int out_size, void* d_ws, size_t ws_size,
                              hipStream_t stream) {
    const float* x       = (const float*)d_in[0];
    const int*   ei      = (const int*)  d_in[1];   // [2, N_EDGES]
    const int*   batch   = (const int*)  d_in[2];
    const float* w1_rel  = (const float*)d_in[3];
    const float* b1_rel  = (const float*)d_in[4];
    const float* w1_root = (const float*)d_in[5];
    const float* w2_rel  = (const float*)d_in[6];
    const float* b2_rel  = (const float*)d_in[7];
    const float* w2_root = (const float*)d_in[8];
    float* out = (float*)d_out;

    const int* src = ei;
    const int* dst = ei + N_EDGES;

    // workspace layout: [agg1 (N*38) | agg2 (N*64) | h (N*64)] floats
    float* agg1 = (float*)d_ws;
    float* agg2 = agg1 + (size_t)N_NODES * F_IN;
    float* h    = agg2 + (size_t)N_NODES * HID;

    // zero agg1 + agg2 in one contiguous memset (40.8 MB)
    hipMemsetAsync(d_ws, 0, (size_t)N_NODES * (F_IN + HID) * sizeof(float), stream);

    {   // scatter1: 60.8M threads
        int total = N_EDGES * F_IN;
        int blocks = (total + 255) / 256;
        scatter1_kernel<<<blocks, 256, 0, stream>>>(x, src, dst, agg1);
    }
    {   // dense1: 64 nodes per block
        int blocks = (N_NODES + 63) / 64;
        dense1_kernel<<<blocks, 256, 0, stream>>>(x, agg1, w1_rel, b1_rel, w1_root, h);
    }
    {   // scatter2: 102.4M threads
        int total = N_EDGES * HID;
        int blocks = (total + 255) / 256;
        scatter2_kernel<<<blocks, 256, 0, stream>>>(h, src, dst, agg2);
    }
    {   // layer2 + mean-pool + relu, one block per graph
        layer2_pool_kernel<<<N_GRAPHS, 256, 0, stream>>>(h, agg2, w2_rel, b2_rel,
                                                         w2_root, batch, out);
    }
}

// Round 2
// 913.255 us; speedup vs baseline: 1.5536x; 1.5536x over previous
//
#include <hip/hip_runtime.h>

#define N_NODES 100000
#define N_EDGES 1600000
#define N_GRAPHS 256
#define F_IN 38
#define HID 64
#define CAP 64   // per-node incoming-edge slot capacity (Poisson(16): max deg ~40)

// ---------------------------------------------------------------------------
// Build bucket-CSR: slots[d*64 + pos] = src, cnt[d] = in-degree.
// 1.6M atomics over 100k counters (vs 163M in the scatter formulation).
// ---------------------------------------------------------------------------
__global__ void csr_build_kernel(const int* __restrict__ src,
                                 const int* __restrict__ dst,
                                 int* __restrict__ cnt,
                                 int* __restrict__ slots) {
    int e = blockIdx.x * blockDim.x + threadIdx.x;
    if (e >= N_EDGES) return;
    int d = dst[e];
    int pos = atomicAdd(&cnt[d], 1);
    if (pos < CAP) slots[(d << 6) + pos] = src[e];
}

// ---------------------------------------------------------------------------
// Layer 1 fused: gather agg1 rows (38-dim, pre-matmul by linearity) + own x
// row into LDS, then h = relu(agg1 @ w1_rel + b1 + x @ w1_root).
// 1563 blocks x 256 threads; 64 nodes/block; LDS ~39KB -> 4 blocks/CU.
// ---------------------------------------------------------------------------
__global__ __launch_bounds__(256) void layer1_kernel(
        const float* __restrict__ x,
        const int* __restrict__ cnt,
        const int* __restrict__ slots,
        const float* __restrict__ w_rel,
        const float* __restrict__ b_rel,
        const float* __restrict__ w_root,
        float* __restrict__ h) {
    __shared__ float s_wrel[F_IN * HID];    // 9.7 KB
    __shared__ float s_wroot[F_IN * HID];   // 9.7 KB
    __shared__ float s_a[64][F_IN];         // 9.7 KB gathered agg rows
    __shared__ float s_x[64][F_IN];         // 9.7 KB own rows
    for (int i = threadIdx.x; i < F_IN * HID; i += 256) {
        s_wrel[i] = w_rel[i];
        s_wroot[i] = w_root[i];
    }
    const int wave = threadIdx.x >> 6, lane = threadIdx.x & 63;
    const int base = blockIdx.x * 64;

    // Phase A: wave w gathers rows for nodes [base+16w, base+16w+16)
    for (int i = 0; i < 16; ++i) {
        int nl = wave * 16 + i;
        int n = base + nl;
        float sum = 0.f, xv = 0.f;
        if (n < N_NODES) {
            if (lane < F_IN) xv = x[n * F_IN + lane];
            int deg = cnt[n]; if (deg > CAP) deg = CAP;
            const int* sl = slots + (n << 6);
            int j = 0;
            for (; j + 4 <= deg; j += 4) {          // 4 gathers in flight
                int4 s4 = *(const int4*)(sl + j);   // 16B-aligned (row is 256B-aligned)
                if (lane < F_IN) {
                    sum += x[s4.x * F_IN + lane];
                    sum += x[s4.y * F_IN + lane];
                    sum += x[s4.z * F_IN + lane];
                    sum += x[s4.w * F_IN + lane];
                }
            }
            for (; j < deg; ++j) {
                int s = sl[j];
                if (lane < F_IN) sum += x[s * F_IN + lane];
            }
        }
        if (lane < F_IN) { s_a[nl][lane] = sum; s_x[nl][lane] = xv; }
    }
    __syncthreads();

    // Phase B: dense from LDS (broadcast reads are conflict-free)
    const int c = lane, r = wave;
    const float bias = b_rel[c];
    for (int i = 0; i < 16; ++i) {
        int nl = r * 16 + i;
        int n = base + nl;
        if (n >= N_NODES) break;
        float acc = bias;
        #pragma unroll
        for (int k = 0; k < F_IN; ++k) {
            acc += s_a[nl][k] * s_wrel[k * HID + c];
            acc += s_x[nl][k] * s_wroot[k * HID + c];
        }
        h[(n << 6) + c] = fmaxf(acc, 0.f);
    }
}

// ---------------------------------------------------------------------------
// Layer 2 fused + pool: gather agg2 rows of h + own h row into LDS, compute
// un-relu'd layer-2 value, accumulate per-graph sums (batch sorted ->
// run-detection, ~1 atomic per thread). h2 never materialized.
// LDS 64KB -> 2 blocks/CU (8 waves).
// ---------------------------------------------------------------------------
__global__ __launch_bounds__(256) void layer2_pool_kernel(
        const float* __restrict__ h,
        const int* __restrict__ cnt,
        const int* __restrict__ slots,
        const float* __restrict__ w_rel,
        const float* __restrict__ b_rel,
        const float* __restrict__ w_root,
        const int* __restrict__ batch,
        float* __restrict__ pooled) {
    __shared__ float s_wrel[HID * HID];     // 16 KB
    __shared__ float s_wroot[HID * HID];    // 16 KB
    __shared__ float s_a[64][HID];          // 16 KB
    __shared__ float s_h[64][HID];          // 16 KB
    for (int i = threadIdx.x; i < HID * HID; i += 256) {
        s_wrel[i] = w_rel[i];
        s_wroot[i] = w_root[i];
    }
    const int wave = threadIdx.x >> 6, lane = threadIdx.x & 63;
    const int base = blockIdx.x * 64;

    // Phase A: gather 256B h-rows, coalesced across 64 lanes
    for (int i = 0; i < 16; ++i) {
        int nl = wave * 16 + i;
        int n = base + nl;
        float sum = 0.f, hv = 0.f;
        if (n < N_NODES) {
            hv = h[(n << 6) + lane];
            int deg = cnt[n]; if (deg > CAP) deg = CAP;
            const int* sl = slots + (n << 6);
            int j = 0;
            for (; j + 4 <= deg; j += 4) {
                int4 s4 = *(const int4*)(sl + j);
                sum += h[(s4.x << 6) + lane];
                sum += h[(s4.y << 6) + lane];
                sum += h[(s4.z << 6) + lane];
                sum += h[(s4.w << 6) + lane];
            }
            for (; j < deg; ++j) sum += h[(sl[j] << 6) + lane];
        }
        s_a[nl][lane] = sum;
        s_h[nl][lane] = hv;
    }
    __syncthreads();

    // Phase B: dense + in-register pooling over sorted batch runs
    const int c = lane, r = wave;
    const float bias = b_rel[c];
    float psum = 0.f;
    int cur_g = -1;
    for (int i = 0; i < 16; ++i) {
        int nl = r * 16 + i;
        int n = base + nl;
        if (n >= N_NODES) break;
        float acc = bias;
        #pragma unroll
        for (int k = 0; k < HID; ++k) {
            acc += s_a[nl][k] * s_wrel[k * HID + c];
            acc += s_h[nl][k] * s_wroot[k * HID + c];
        }
        int g = batch[n];   // wave-broadcast load, cached
        if (g != cur_g) {
            if (cur_g >= 0) atomicAdd(&pooled[(cur_g << 6) + c], psum);
            psum = 0.f;
            cur_g = g;
        }
        psum += acc;
    }
    if (cur_g >= 0) atomicAdd(&pooled[(cur_g << 6) + c], psum);
}

// ---------------------------------------------------------------------------
// out[g][c] = relu(pooled[g][c] / max(count_g, 1)); counts via binary search
// ---------------------------------------------------------------------------
__global__ void finalize_kernel(const float* __restrict__ pooled,
                                const int* __restrict__ batch,
                                float* __restrict__ out) {
    int idx = blockIdx.x * blockDim.x + threadIdx.x;
    if (idx >= N_GRAPHS * HID) return;
    int g = idx >> 6;
    int lo = 0, hi = N_NODES;
    while (lo < hi) { int m = (lo + hi) >> 1; if (batch[m] < g) lo = m + 1; else hi = m; }
    int start = lo;
    hi = N_NODES;
    while (lo < hi) { int m = (lo + hi) >> 1; if (batch[m] < g + 1) lo = m + 1; else hi = m; }
    int cntg = lo - start;
    float denom = cntg > 0 ? (float)cntg : 1.f;
    out[idx] = fmaxf(pooled[idx] / denom, 0.f);
}

// ---------------------------------------------------------------------------
extern "C" void kernel_launch(void* const* d_in, const int* in_sizes, int n_in,
                              void* d_out, int out_size, void* d_ws, size_t ws_size,
                              hipStream_t stream) {
    const float* x       = (const float*)d_in[0];
    const int*   ei      = (const int*)  d_in[1];   // [2, N_EDGES]
    const int*   batch   = (const int*)  d_in[2];
    const float* w1_rel  = (const float*)d_in[3];
    const float* b1_rel  = (const float*)d_in[4];
    const float* w1_root = (const float*)d_in[5];
    const float* w2_rel  = (const float*)d_in[6];
    const float* b2_rel  = (const float*)d_in[7];
    const float* w2_root = (const float*)d_in[8];
    float* out = (float*)d_out;

    const int* src = ei;
    const int* dst = ei + N_EDGES;

    // ws layout (bytes):
    //   [0, 400000)                cnt    : N_NODES int          (zeroed)
    //   [400000, 465536)           pooled : 256*64 float         (zeroed)
    //   [465536, 26065536)         slots  : N_NODES*64 int
    //   [26065536, 51665536)       h      : N_NODES*64 float
    char* wsb = (char*)d_ws;
    int*   cnt    = (int*)  (wsb);
    float* pooled = (float*)(wsb + 400000);
    int*   slots  = (int*)  (wsb + 465536);
    float* h      = (float*)(wsb + 26065536);

    hipMemsetAsync(wsb, 0, 465536, stream);  // cnt + pooled only

    {   // CSR build
        int blocks = (N_EDGES + 255) / 256;
        csr_build_kernel<<<blocks, 256, 0, stream>>>(src, dst, cnt, slots);
    }
    {   // layer 1 (gather + dense + relu)
        int blocks = (N_NODES + 63) / 64;
        layer1_kernel<<<blocks, 256, 0, stream>>>(x, cnt, slots, w1_rel, b1_rel,
                                                  w1_root, h);
    }
    {   // layer 2 (gather + dense) + pooled sums
        int blocks = (N_NODES + 63) / 64;
        layer2_pool_kernel<<<blocks, 256, 0, stream>>>(h, cnt, slots, w2_rel, b2_rel,
                                                       w2_root, batch, pooled);
    }
    {   // mean + relu
        int blocks = (N_GRAPHS * HID + 255) / 256;
        finalize_kernel<<<blocks, 256, 0, stream>>>(pooled, batch, out);
    }
}

// Round 3
// 583.327 us; speedup vs baseline: 2.4323x; 1.5656x over previous
//
#include <hip/hip_runtime.h>

#define N_NODES 100000
#define N_EDGES 1600000
#define N_GRAPHS 256
#define F_IN 38
#define F_PAD 40   // x packed to 40 bf16 (80 B rows, 16B-aligned)
#define HID 64
#define CAP 64     // per-node incoming-edge slot capacity (Poisson(16))

__device__ __forceinline__ float b2f(unsigned short u) {
    union { unsigned int i; float f; } v; v.i = ((unsigned int)u) << 16; return v.f;
}
__device__ __forceinline__ unsigned short f2b(float f) {
    union { float f; unsigned int i; } v; v.f = f;
    unsigned int lsb = (v.i >> 16) & 1u;
    return (unsigned short)((v.i + 0x7fffu + lsb) >> 16);
}

// ---------------------------------------------------------------------------
// Pack x [N][38] fp32 -> xb [N][40] bf16 (zero-padded)
// ---------------------------------------------------------------------------
__global__ void pack_x_kernel(const float* __restrict__ x,
                              unsigned short* __restrict__ xb) {
    int tid = blockIdx.x * blockDim.x + threadIdx.x;
    if (tid >= N_NODES * F_PAD) return;
    int n = tid / F_PAD;
    int f = tid - n * F_PAD;
    float v = (f < F_IN) ? x[n * F_IN + f] : 0.0f;
    xb[tid] = f2b(v);
}

// ---------------------------------------------------------------------------
// Bucket-CSR: slots[d*64+pos] = src, cnt[d] = in-degree (1.6M atomics)
// ---------------------------------------------------------------------------
__global__ void csr_build_kernel(const int* __restrict__ src,
                                 const int* __restrict__ dst,
                                 int* __restrict__ cnt,
                                 int* __restrict__ slots) {
    int e = blockIdx.x * blockDim.x + threadIdx.x;
    if (e >= N_EDGES) return;
    int d = dst[e];
    int pos = atomicAdd(&cnt[d], 1);
    if (pos < CAP) slots[(d << 6) + pos] = src[e];
}

// ---------------------------------------------------------------------------
// Layer 1 fused: gather agg1 (bf16 x-rows, fp32 accum) + own x row (fp32),
// h = relu(agg1@w1_rel + b1 + x@w1_root) stored as bf16, AND per-graph
// sum of h rows (hsum) pooled in-register (batch sorted -> run detection).
// LDS ~39.4 KB -> 4 blocks/CU; launch_bounds(256,4) caps VGPR<=128.
// ---------------------------------------------------------------------------
__global__ __launch_bounds__(256, 4) void layer1_kernel(
        const float* __restrict__ x,
        const unsigned short* __restrict__ xb,
        const int* __restrict__ cnt,
        const int* __restrict__ slots,
        const float* __restrict__ w_rel,
        const float* __restrict__ b_rel,
        const float* __restrict__ w_root,
        const int* __restrict__ batch,
        unsigned short* __restrict__ hb,
        float* __restrict__ hsum) {
    __shared__ float s_wrel[F_IN * HID];    // 9.5 KB
    __shared__ float s_wroot[F_IN * HID];   // 9.5 KB
    __shared__ float s_a[64][F_PAD];        // 10 KB
    __shared__ float s_x[64][F_IN];         // 9.5 KB
    for (int i = threadIdx.x; i < F_IN * HID; i += 256) {
        s_wrel[i] = w_rel[i];
        s_wroot[i] = w_root[i];
    }
    const int wave = threadIdx.x >> 6, lane = threadIdx.x & 63;
    const int base = blockIdx.x * 64;

    // Phase A: wave gathers rows for its 16 nodes; 8 loads in flight
    for (int i = 0; i < 16; ++i) {
        int nl = wave * 16 + i;
        int n = base + nl;
        float sum = 0.f;
        if (n < N_NODES) {
            if (lane < F_IN) s_x[nl][lane] = x[n * F_IN + lane];
            if (lane < F_PAD) {
                int deg = cnt[n]; if (deg > CAP) deg = CAP;
                const int* sl = slots + (n << 6);
                int j = 0;
                for (; j + 8 <= deg; j += 8) {
                    int4 a4 = *(const int4*)(sl + j);
                    int4 b4 = *(const int4*)(sl + j + 4);
                    unsigned short t0 = xb[a4.x * F_PAD + lane];
                    unsigned short t1 = xb[a4.y * F_PAD + lane];
                    unsigned short t2 = xb[a4.z * F_PAD + lane];
                    unsigned short t3 = xb[a4.w * F_PAD + lane];
                    unsigned short t4 = xb[b4.x * F_PAD + lane];
                    unsigned short t5 = xb[b4.y * F_PAD + lane];
                    unsigned short t6 = xb[b4.z * F_PAD + lane];
                    unsigned short t7 = xb[b4.w * F_PAD + lane];
                    sum += b2f(t0) + b2f(t1) + b2f(t2) + b2f(t3);
                    sum += b2f(t4) + b2f(t5) + b2f(t6) + b2f(t7);
                }
                for (; j < deg; ++j) sum += b2f(xb[sl[j] * F_PAD + lane]);
                s_a[nl][lane] = sum;
            }
        }
    }
    __syncthreads();

    // Phase B: dense from LDS + bf16 store + per-graph pooling of h
    const int c = lane, r = wave;
    const float bias = b_rel[c];
    float psum = 0.f;
    int cur_g = -1;
    for (int i = 0; i < 16; ++i) {
        int nl = r * 16 + i;
        int n = base + nl;
        if (n >= N_NODES) break;
        float acc = bias;
        #pragma unroll
        for (int k = 0; k < F_IN; ++k) {
            acc += s_a[nl][k] * s_wrel[k * HID + c];
            acc += s_x[nl][k] * s_wroot[k * HID + c];
        }
        float hv = fmaxf(acc, 0.f);
        hb[(n << 6) + c] = f2b(hv);
        int g = batch[n];  // wave-uniform, cached
        if (g != cur_g) {
            if (cur_g >= 0) atomicAdd(&hsum[(cur_g << 6) + c], psum);
            psum = 0.f;
            cur_g = g;
        }
        psum += hv;
    }
    if (cur_g >= 0) atomicAdd(&hsum[(cur_g << 6) + c], psum);
}

// ---------------------------------------------------------------------------
// Layer 2 (rel half only): gather agg2 (bf16 h-rows, fp32 accum), compute
// agg2 @ w2_rel, pool per-graph sums (pooled_rel). Root+bias handled in
// finalize via hsum. LDS 32 KB -> 4 blocks/CU (16 waves).
// ---------------------------------------------------------------------------
__global__ __launch_bounds__(256, 4) void layer2_kernel(
        const unsigned short* __restrict__ hb,
        const int* __restrict__ cnt,
        const int* __restrict__ slots,
        const float* __restrict__ w_rel,
        const int* __restrict__ batch,
        float* __restrict__ pooled_rel) {
    __shared__ float s_wrel[HID * HID];     // 16 KB
    __shared__ float s_a[64][HID];          // 16 KB
    for (int i = threadIdx.x; i < HID * HID; i += 256) s_wrel[i] = w_rel[i];
    const int wave = threadIdx.x >> 6, lane = threadIdx.x & 63;
    const int base = blockIdx.x * 64;

    // Phase A: gather 128 B bf16 h-rows, 8 loads in flight
    for (int i = 0; i < 16; ++i) {
        int nl = wave * 16 + i;
        int n = base + nl;
        float sum = 0.f;
        if (n < N_NODES) {
            int deg = cnt[n]; if (deg > CAP) deg = CAP;
            const int* sl = slots + (n << 6);
            int j = 0;
            for (; j + 8 <= deg; j += 8) {
                int4 a4 = *(const int4*)(sl + j);
                int4 b4 = *(const int4*)(sl + j + 4);
                unsigned short t0 = hb[(a4.x << 6) + lane];
                unsigned short t1 = hb[(a4.y << 6) + lane];
                unsigned short t2 = hb[(a4.z << 6) + lane];
                unsigned short t3 = hb[(a4.w << 6) + lane];
                unsigned short t4 = hb[(b4.x << 6) + lane];
                unsigned short t5 = hb[(b4.y << 6) + lane];
                unsigned short t6 = hb[(b4.z << 6) + lane];
                unsigned short t7 = hb[(b4.w << 6) + lane];
                sum += b2f(t0) + b2f(t1) + b2f(t2) + b2f(t3);
                sum += b2f(t4) + b2f(t5) + b2f(t6) + b2f(t7);
            }
            for (; j < deg; ++j) sum += b2f(hb[(sl[j] << 6) + lane]);
        }
        s_a[nl][lane] = sum;
    }
    __syncthreads();

    // Phase B: agg2 @ w2_rel + per-graph pooling (no bias, no root here)
    const int c = lane, r = wave;
    float psum = 0.f;
    int cur_g = -1;
    for (int i = 0; i < 16; ++i) {
        int nl = r * 16 + i;
        int n = base + nl;
        if (n >= N_NODES) break;
        float acc = 0.f;
        #pragma unroll
        for (int k = 0; k < HID; ++k) acc += s_a[nl][k] * s_wrel[k * HID + c];
        int g = batch[n];
        if (g != cur_g) {
            if (cur_g >= 0) atomicAdd(&pooled_rel[(cur_g << 6) + c], psum);
            psum = 0.f;
            cur_g = g;
        }
        psum += acc;
    }
    if (cur_g >= 0) atomicAdd(&pooled_rel[(cur_g << 6) + c], psum);
}

// ---------------------------------------------------------------------------
// out[g][c] = relu( (pooled_rel + hsum@w2_root + cnt*b2) / max(cnt,1) )
// one block (1 wave, 64 threads) per graph
// ---------------------------------------------------------------------------
__global__ void finalize_kernel(const float* __restrict__ pooled_rel,
                                const float* __restrict__ hsum,
                                const float* __restrict__ w2_root,
                                const float* __restrict__ b2,
                                const int* __restrict__ batch,
                                float* __restrict__ out) {
    __shared__ float s_h[HID];
    const int g = blockIdx.x;
    const int c = threadIdx.x;
    s_h[c] = hsum[(g << 6) + c];
    __syncthreads();

    int lo = 0, hi = N_NODES;
    while (lo < hi) { int m = (lo + hi) >> 1; if (batch[m] < g) lo = m + 1; else hi = m; }
    int start = lo;
    hi = N_NODES;
    while (lo < hi) { int m = (lo + hi) >> 1; if (batch[m] < g + 1) lo = m + 1; else hi = m; }
    int cntg = lo - start;

    float acc = pooled_rel[(g << 6) + c] + (float)cntg * b2[c];
    #pragma unroll
    for (int k = 0; k < HID; ++k) acc += s_h[k] * w2_root[k * HID + c];
    float denom = cntg > 0 ? (float)cntg : 1.f;
    out[(g << 6) + c] = fmaxf(acc / denom, 0.f);
}

// ---------------------------------------------------------------------------
extern "C" void kernel_launch(void* const* d_in, const int* in_sizes, int n_in,
                              void* d_out, int out_size, void* d_ws, size_t ws_size,
                              hipStream_t stream) {
    const float* x       = (const float*)d_in[0];
    const int*   ei      = (const int*)  d_in[1];
    const int*   batch   = (const int*)  d_in[2];
    const float* w1_rel  = (const float*)d_in[3];
    const float* b1_rel  = (const float*)d_in[4];
    const float* w1_root = (const float*)d_in[5];
    const float* w2_rel  = (const float*)d_in[6];
    const float* b2_rel  = (const float*)d_in[7];
    const float* w2_root = (const float*)d_in[8];
    float* out = (float*)d_out;

    const int* src = ei;
    const int* dst = ei + N_EDGES;

    // ws layout (bytes):
    //   [0,        400000)   cnt        N int        (zeroed)
    //   [400384,   465920)   hsum       256*64 f32   (zeroed)
    //   [465920,   531456)   pooled_rel 256*64 f32   (zeroed)
    //   [531456, 26131456)   slots      N*64 int
    //   [26131456,34131456)  xb         N*40 bf16
    //   [34131456,46931456)  hb         N*64 bf16
    char* wsb = (char*)d_ws;
    int*            cnt        = (int*)           (wsb);
    float*          hsum       = (float*)         (wsb + 400384);
    float*          pooled_rel = (float*)         (wsb + 465920);
    int*            slots      = (int*)           (wsb + 531456);
    unsigned short* xb         = (unsigned short*)(wsb + 26131456);
    unsigned short* hb         = (unsigned short*)(wsb + 34131456);

    hipMemsetAsync(wsb, 0, 531456, stream);

    {   // pack x -> bf16 [N][40]
        int total = N_NODES * F_PAD;
        pack_x_kernel<<<(total + 255) / 256, 256, 0, stream>>>(x, xb);
    }
    {   // CSR build
        csr_build_kernel<<<(N_EDGES + 255) / 256, 256, 0, stream>>>(src, dst, cnt, slots);
    }
    {   // layer 1 (gather + dense + relu + hsum pooling)
        int blocks = (N_NODES + 63) / 64;
        layer1_kernel<<<blocks, 256, 0, stream>>>(x, xb, cnt, slots, w1_rel, b1_rel,
                                                  w1_root, batch, hb, hsum);
    }
    {   // layer 2 rel-half (gather + dense + pooling)
        int blocks = (N_NODES + 63) / 64;
        layer2_kernel<<<blocks, 256, 0, stream>>>(hb, cnt, slots, w2_rel, batch,
                                                  pooled_rel);
    }
    {   // finalize: root GEMM + bias + mean + relu
        finalize_kernel<<<N_GRAPHS, HID, 0, stream>>>(pooled_rel, hsum, w2_root,
                                                      b2_rel, batch, out);
    }
}